// Round 5
// baseline (223.533 us; speedup 1.0000x reference)
//
#include <hip/hip_runtime.h>
#include <hip/hip_bf16.h>

typedef __hip_bfloat16 bf16;
typedef unsigned short ush;
typedef __attribute__((ext_vector_type(8))) short bf16x8;
typedef __attribute__((ext_vector_type(4))) float f32x4;

#define BB 2
#define TT 2048
#define DD 1024
#define HH 16
#define DHH 64
#define MM (BB*TT)      // 4096 rows
#define N3 (3*DD)       // 3072

__device__ __forceinline__ bf16  f2b(float x){ return __float2bfloat16(x); }
__device__ __forceinline__ ush   f2bu(float x){ bf16 h = __float2bfloat16(x); return *(ush*)&h; }

#define GLOAD_LDS(gp, lp) \
    __builtin_amdgcn_global_load_lds( \
        (const __attribute__((address_space(1))) void*)(gp), \
        (__attribute__((address_space(3))) void*)(lp), 16, 0, 0)

// ---------------------------------------------------------------------------
// cvt_x: x f32 [4096][1024] -> bf16 into d_out's out_a region (dead there
// until proj_mfma overwrites it).
// ---------------------------------------------------------------------------
__global__ __launch_bounds__(256) void cvt_x(
    const float* __restrict__ src, ush* __restrict__ dst)
{
    const size_t i = ((size_t)blockIdx.x * 256 + threadIdx.x) * 8;
    float4 a = *(const float4*)&src[i];
    float4 b = *(const float4*)&src[i + 4];
    ushort4 u0; u0.x = f2bu(a.x); u0.y = f2bu(a.y); u0.z = f2bu(a.z); u0.w = f2bu(a.w);
    ushort4 u1; u1.x = f2bu(b.x); u1.y = f2bu(b.y); u1.z = f2bu(b.z); u1.w = f2bu(b.w);
    *(ushort4*)&dst[i] = u0;
    *(ushort4*)&dst[i + 4] = u1;
}

// ---------------------------------------------------------------------------
// Transpose+convert: dst[c][r] = bf16(src[r][c]). src is [R][C] f32.
// ---------------------------------------------------------------------------
__global__ __launch_bounds__(256) void transpose_cvt(
    const float* __restrict__ src, ush* __restrict__ dst, int R, int C)
{
    __shared__ ush T[64][68];
    const int tid = threadIdx.x;
    const int c0 = blockIdx.x * 64;
    const int r0 = blockIdx.y * 64;

    #pragma unroll
    for (int it = 0; it < 4; it++) {
        int idx = it * 256 + tid;
        int i = idx >> 4, jf = idx & 15;
        float4 v = *(const float4*)&src[(size_t)(r0 + i) * C + c0 + jf * 4];
        T[jf * 4 + 0][i] = f2bu(v.x);
        T[jf * 4 + 1][i] = f2bu(v.y);
        T[jf * 4 + 2][i] = f2bu(v.z);
        T[jf * 4 + 3][i] = f2bu(v.w);
    }
    __syncthreads();
    #pragma unroll
    for (int it = 0; it < 4; it++) {
        int idx = it * 256 + tid;
        int j = idx >> 4, i4 = idx & 15;
        *(ushort4*)&dst[(size_t)(c0 + j) * R + r0 + i4 * 4] =
            *(const ushort4*)&T[j][i4 * 4];
    }
}

// ---------------------------------------------------------------------------
// Kernel 1: QKV MFMA GEMM, m97 structure (global_load_lds width=16, linear
// LDS). Fast path (write_bf=1) pre-scales q by 0.25*log2(e) so the flash
// kernel's exp2 needs NO multiply (relative bf16 rounding error is scale-
// invariant). Fallback path (write_bf=0) writes unscaled q.
// ---------------------------------------------------------------------------
__global__ __launch_bounds__(256) void qkv_mfma(
    const ush* __restrict__ xbf, const ush* __restrict__ wT,
    const float* __restrict__ bias,
    bf16* __restrict__ qws, float* __restrict__ kout, float* __restrict__ vout,
    ush* __restrict__ kbf, ush* __restrict__ vtb, int write_bf)
{
    __shared__ __align__(16) ush As[128 * 32];
    __shared__ __align__(16) ush Bs[128 * 32];

    const int tid  = threadIdx.x;
    const int lane = tid & 63;
    const int w    = tid >> 6;
    const int n16  = lane & 15;
    const int quad = lane >> 4;
    const int row0 = blockIdx.y * 128;
    const int col0 = blockIdx.x * 128;
    const int wrow = (w >> 1) * 64;
    const int wcol = (w & 1) * 64;

    f32x4 acc[4][4];
    #pragma unroll
    for (int mb = 0; mb < 4; mb++)
        #pragma unroll
        for (int nb = 0; nb < 4; nb++) acc[mb][nb] = (f32x4){0.f,0.f,0.f,0.f};

    for (int kk0 = 0; kk0 < DD; kk0 += 32) {
        __syncthreads();
        #pragma unroll
        for (int it = 0; it < 2; it++) {
            int c = it * 256 + tid;
            int r = c >> 2, co = (c & 3) * 8;
            GLOAD_LDS(&xbf[(size_t)(row0 + r) * DD + kk0 + co], &As[c * 8]);
            GLOAD_LDS(&wT[(size_t)(col0 + r) * DD + kk0 + co], &Bs[c * 8]);
        }
        __syncthreads();

        bf16x8 af[4];
        #pragma unroll
        for (int mb = 0; mb < 4; mb++)
            af[mb] = *(const bf16x8*)&As[(wrow + mb * 16 + n16) * 32 + quad * 8];
        #pragma unroll
        for (int nb = 0; nb < 4; nb++) {
            bf16x8 bfr = *(const bf16x8*)&Bs[(wcol + nb * 16 + n16) * 32 + quad * 8];
            #pragma unroll
            for (int mb = 0; mb < 4; mb++)
                acc[mb][nb] = __builtin_amdgcn_mfma_f32_16x16x32_bf16(
                    af[mb], bfr, acc[mb][nb], 0, 0, 0);
        }
    }

    const float qsc = write_bf ? 0.36067376022224085f : 1.0f; // 0.25*log2(e)

    #pragma unroll
    for (int nb = 0; nb < 4; nb++) {
        const int gc = col0 + wcol + nb * 16 + n16;
        const float bv = bias[gc];
        const int which = gc >> 10;
        const int h = (gc & 1023) >> 6;
        const int d = gc & 63;
        #pragma unroll
        for (int mb = 0; mb < 4; mb++) {
            float vv[4];
            #pragma unroll
            for (int reg = 0; reg < 4; reg++) vv[reg] = acc[mb][nb][reg] + bv;
            const int gr0 = row0 + wrow + mb * 16 + quad * 4;  // 4 consecutive rows
            const int b_ = gr0 >> 11, t0 = gr0 & 2047;
            const int bh = b_ * HH + h;
            const size_t tbase = ((size_t)bh * TT + t0) * DHH + d;
            if (which == 0) {
                #pragma unroll
                for (int reg = 0; reg < 4; reg++)
                    qws[tbase + (size_t)reg * DHH] = f2b(vv[reg] * qsc);
            } else if (which == 1) {
                #pragma unroll
                for (int reg = 0; reg < 4; reg++) kout[tbase + (size_t)reg * DHH] = vv[reg];
                if (write_bf) {
                    #pragma unroll
                    for (int reg = 0; reg < 4; reg++)
                        kbf[tbase + (size_t)reg * DHH] = f2bu(vv[reg]);
                }
            } else {
                #pragma unroll
                for (int reg = 0; reg < 4; reg++) vout[tbase + (size_t)reg * DHH] = vv[reg];
                if (write_bf) {
                    ushort4 u;
                    u.x = f2bu(vv[0]); u.y = f2bu(vv[1]);
                    u.z = f2bu(vv[2]); u.w = f2bu(vv[3]);
                    *(ushort4*)&vtb[((size_t)bh * DHH + d) * TT + t0] = u;
                }
            }
        }
    }
}

// ---------------------------------------------------------------------------
// Kernel 2 FAST PATH v4: pipelined + conflict-free pitch.
//  - LDS pitch 70 shorts (35 dwords == 3 mod 32): fragment reads
//    (bank = 3*n16 + 4*quad) spread ~2-way (free) vs pitch 72's 8-way.
//  - Double-buffered Ks/Vt; QK(kt+1) MFMAs are issued BEFORE the exp-phase
//    of tile kt, so the matrix pipe crunches the next tile's scores while
//    the VALU runs exp/cvt/Ps for the current tile (R4: MfmaUtil 12 vs
//    VALUBusy 47 = serial chain).
//  - exp2f(s) with NO multiply (q pre-scaled by 0.25*log2e in qkv).
//  - Causal mask computed ONLY on the diagonal tile (kt==qi); interior
//    tiles are provably unmasked (64*kt+63 <= 64*qi).
//  - Same 2 barriers/tile; Ps stays same-wave (no barrier).
// ---------------------------------------------------------------------------
#define FP 70   // LDS pitch in shorts

__global__ __launch_bounds__(256) void flash_attn_v4(
    const ush* __restrict__ qin, const ush* __restrict__ kbf,
    const ush* __restrict__ vtb, bf16* __restrict__ attn)
{
    __shared__ __align__(16) ush Ks[2][64][FP];
    __shared__ __align__(16) ush Vt[2][64][FP];
    __shared__ __align__(16) ush Ps[4][16][FP];

    const int tid  = threadIdx.x;
    const int lane = tid & 63;
    const int w    = tid >> 6;
    const int n16  = lane & 15;
    const int quad = lane >> 4;
    const int bh = blockIdx.y;       // 0..31
    const int qi = (bh & 8) ? (31 - (int)blockIdx.x) : (int)blockIdx.x;
    const int q0 = qi * 64;
    const ush* Qb  = qin + (size_t)bh * TT * DHH;
    const ush* Kb  = kbf + (size_t)bh * TT * DHH;
    const ush* Vtb = vtb + (size_t)bh * DHH * TT;
    const int b_ = bh >> 4, h = bh & 15;

    // Q fragments (pre-scaled by 0.25*log2e) straight to registers
    const ush* Qp = Qb + (size_t)(q0 + w * 16 + n16) * DHH + quad * 8;
    const bf16x8 qa0 = *(const bf16x8*)&Qp[0];
    const bf16x8 qa1 = *(const bf16x8*)&Qp[32];

    const int r0c = tid >> 3, c8c = (tid & 7) * 8;
    const int r1c = (256 + tid) >> 3, c8c1 = ((256 + tid) & 7) * 8;

    bf16x8 kst[2], vst[2];
#define LOAD_TILE(kt) do { \
        const ush* Kp_ = Kb + (size_t)((kt) * 64) * DHH; \
        const ush* Vp_ = Vtb + (kt) * 64; \
        kst[0] = *(const bf16x8*)&Kp_[(size_t)r0c * DHH + c8c]; \
        kst[1] = *(const bf16x8*)&Kp_[(size_t)r1c * DHH + c8c1]; \
        vst[0] = *(const bf16x8*)&Vp_[(size_t)r0c * TT + c8c]; \
        vst[1] = *(const bf16x8*)&Vp_[(size_t)r1c * TT + c8c1]; \
    } while(0)
#define STORE_TILE(b) do { \
        *(bf16x8*)&Ks[b][r0c][c8c]  = kst[0]; \
        *(bf16x8*)&Ks[b][r1c][c8c1] = kst[1]; \
        *(bf16x8*)&Vt[b][r0c][c8c]  = vst[0]; \
        *(bf16x8*)&Vt[b][r1c][c8c1] = vst[1]; \
    } while(0)
#define QKT(b, sdst) do { \
        _Pragma("unroll") \
        for (int cb_ = 0; cb_ < 4; cb_++) { \
            bf16x8 kb0_ = *(const bf16x8*)&Ks[b][cb_ * 16 + n16][quad * 8]; \
            bf16x8 kb1_ = *(const bf16x8*)&Ks[b][cb_ * 16 + n16][32 + quad * 8]; \
            f32x4 a4_ = (f32x4){0.f, 0.f, 0.f, 0.f}; \
            a4_ = __builtin_amdgcn_mfma_f32_16x16x32_bf16(qa0, kb0_, a4_, 0, 0, 0); \
            a4_ = __builtin_amdgcn_mfma_f32_16x16x32_bf16(qa1, kb1_, a4_, 0, 0, 0); \
            sdst[cb_] = a4_; \
        } \
    } while(0)

    f32x4 o[4];
    #pragma unroll
    for (int db = 0; db < 4; db++) o[db] = (f32x4){0.f, 0.f, 0.f, 0.f};
    float lsum[4] = {0.f, 0.f, 0.f, 0.f};

    // prologue: tile 0
    LOAD_TILE(0);
    STORE_TILE(0);
    __syncthreads();
    if (qi > 0) LOAD_TILE(1);
    f32x4 s[4], sn[4];
    QKT(0, s);
    int cur = 0;

    for (int kt = 0; kt <= qi; kt++) {
        const bool haveNext = (kt < qi);
        if (haveNext) {
            __syncthreads();           // all waves done PV-reading buf cur^1 (kt-1)
            STORE_TILE(cur ^ 1);
            __syncthreads();           // staged tile kt+1 visible
            if (kt + 2 <= qi) LOAD_TILE(kt + 2);
            QKT(cur ^ 1, sn);          // matrix pipe works during exp below
        }

        // exp phase (VALU). Mask only on the diagonal tile.
        if (kt == qi) {
            const int rloc = w * 16 + quad * 4;   // local row base in tile
            #pragma unroll
            for (int reg = 0; reg < 4; reg++) {
                #pragma unroll
                for (int cb = 0; cb < 4; cb++) {
                    float p = exp2f(s[cb][reg]);
                    if (cb * 16 + n16 > rloc + reg) p = 0.f;
                    lsum[reg] += p;
                    Ps[w][quad * 4 + reg][cb * 16 + n16] = f2bu(p);
                }
            }
        } else {
            #pragma unroll
            for (int reg = 0; reg < 4; reg++) {
                #pragma unroll
                for (int cb = 0; cb < 4; cb++) {
                    float p = exp2f(s[cb][reg]);
                    lsum[reg] += p;
                    Ps[w][quad * 4 + reg][cb * 16 + n16] = f2bu(p);
                }
            }
        }
        // NO barrier: Ps[w] is same-wave (lgkmcnt ordering)

        bf16x8 pa0 = *(const bf16x8*)&Ps[w][n16][quad * 8];
        bf16x8 pa1 = *(const bf16x8*)&Ps[w][n16][32 + quad * 8];
        #pragma unroll
        for (int db = 0; db < 4; db++) {
            bf16x8 vb0 = *(const bf16x8*)&Vt[cur][db * 16 + n16][quad * 8];
            bf16x8 vb1 = *(const bf16x8*)&Vt[cur][db * 16 + n16][32 + quad * 8];
            o[db] = __builtin_amdgcn_mfma_f32_16x16x32_bf16(pa0, vb0, o[db], 0, 0, 0);
            o[db] = __builtin_amdgcn_mfma_f32_16x16x32_bf16(pa1, vb1, o[db], 0, 0, 0);
        }

        if (haveNext) {
            #pragma unroll
            for (int c2 = 0; c2 < 4; c2++) s[c2] = sn[c2];
            cur ^= 1;
        }
    }

    const int grow_base = q0 + w * 16 + quad * 4;
    #pragma unroll
    for (int reg = 0; reg < 4; reg++) {
        float ls = lsum[reg];
        #pragma unroll
        for (int off = 1; off < 16; off <<= 1)
            ls += __shfl_xor(ls, off);
        const float il = 1.0f / ls;
        const int t_ = grow_base + reg;
        bf16* outr = attn + ((size_t)(b_ * TT + t_)) * DD + h * 64 + n16;
        #pragma unroll
        for (int db = 0; db < 4; db++)
            outr[db * 16] = f2b(o[db][reg] * il);
    }
#undef LOAD_TILE
#undef STORE_TILE
#undef QKT
}

// ---------------------------------------------------------------------------
// Kernel 2 FALLBACK (exact R7 kernel): f32 K/V from d_out, unscaled q.
// ---------------------------------------------------------------------------
__global__ __launch_bounds__(256) void flash_attn_mfma(
    const bf16* __restrict__ qin, const float* __restrict__ kin,
    const float* __restrict__ vin, bf16* __restrict__ attn)
{
    __shared__ __align__(16) ush Qs[64][72];
    __shared__ __align__(16) ush Ks[64][72];
    __shared__ __align__(16) ush Vt[64][72];
    __shared__ __align__(16) ush Ps[4][16][72];

    const int tid  = threadIdx.x;
    const int lane = tid & 63;
    const int w    = tid >> 6;
    const int n16  = lane & 15;
    const int quad = lane >> 4;
    const int qi = blockIdx.x;
    const int bh = blockIdx.y;
    const int q0 = qi * 64;

    const ush*   Qp = (const ush*)qin + ((size_t)bh * TT + q0) * DHH;
    const float* Kb = kin + (size_t)bh * TT * DHH;
    const float* Vb = vin + (size_t)bh * TT * DHH;

    #pragma unroll
    for (int it = 0; it < 4; it++) {
        int idx = (it * 256 + tid) * 4;
        int r = idx >> 6, d = idx & 63;
        *(ushort4*)&Qs[r][d] = *(const ushort4*)&Qp[idx];
    }

    f32x4 o[4];
    #pragma unroll
    for (int db = 0; db < 4; db++) o[db] = (f32x4){0.f, 0.f, 0.f, 0.f};
    float m_old[4] = {-1e30f, -1e30f, -1e30f, -1e30f};
    float l_run[4] = {0.f, 0.f, 0.f, 0.f};

    for (int kt = 0; kt <= qi; kt++) {
        const float* Kp = Kb + (size_t)(kt * 64) * DHH;
        const float* Vp = Vb + (size_t)(kt * 64) * DHH;
        __syncthreads();
        #pragma unroll
        for (int it = 0; it < 4; it++) {
            int idx = (it * 256 + tid) * 4;
            int c = idx >> 6, d = idx & 63;
            float4 kv = *(const float4*)&Kp[idx];
            ushort4 kb;
            kb.x = f2bu(kv.x); kb.y = f2bu(kv.y); kb.z = f2bu(kv.z); kb.w = f2bu(kv.w);
            *(ushort4*)&Ks[c][d] = kb;
        }
        #pragma unroll
        for (int it = 0; it < 4; it++) {
            int c = tid & 63, d0 = (tid >> 6) * 4 + it * 16;
            float4 vv = *(const float4*)&Vp[c * 64 + d0];
            Vt[d0 + 0][c] = f2bu(vv.x);
            Vt[d0 + 1][c] = f2bu(vv.y);
            Vt[d0 + 2][c] = f2bu(vv.z);
            Vt[d0 + 3][c] = f2bu(vv.w);
        }
        __syncthreads();

        bf16x8 qa0 = *(const bf16x8*)&Qs[w * 16 + n16][quad * 8];
        bf16x8 qa1 = *(const bf16x8*)&Qs[w * 16 + n16][32 + quad * 8];
        f32x4 s[4];
        #pragma unroll
        for (int cb = 0; cb < 4; cb++) {
            bf16x8 kb0 = *(const bf16x8*)&Ks[cb * 16 + n16][quad * 8];
            bf16x8 kb1 = *(const bf16x8*)&Ks[cb * 16 + n16][32 + quad * 8];
            f32x4 acc = (f32x4){0.f, 0.f, 0.f, 0.f};
            acc = __builtin_amdgcn_mfma_f32_16x16x32_bf16(qa0, kb0, acc, 0, 0, 0);
            acc = __builtin_amdgcn_mfma_f32_16x16x32_bf16(qa1, kb1, acc, 0, 0, 0);
            s[cb] = acc;
        }

        const int grow_base = q0 + w * 16 + quad * 4;
        const int gcol_base = kt * 64 + n16;
        #pragma unroll
        for (int reg = 0; reg < 4; reg++) {
            float sv[4];
            float pm = -1e30f;
            #pragma unroll
            for (int cb = 0; cb < 4; cb++) {
                float v = s[cb][reg] * 0.25f;
                if (gcol_base + cb * 16 > grow_base + reg) v = -1e10f;
                sv[cb] = v;
                pm = fmaxf(pm, v);
            }
            #pragma unroll
            for (int off = 1; off < 16; off <<= 1)
                pm = fmaxf(pm, __shfl_xor(pm, off));
            float mnew = fmaxf(m_old[reg], pm);
            float alpha = __expf(m_old[reg] - mnew);
            float ps = 0.f;
            #pragma unroll
            for (int cb = 0; cb < 4; cb++) {
                float p = __expf(sv[cb] - mnew);
                Ps[w][quad * 4 + reg][cb * 16 + n16] = f2bu(p);
                ps += p;
            }
            #pragma unroll
            for (int off = 1; off < 16; off <<= 1)
                ps += __shfl_xor(ps, off);
            l_run[reg] = l_run[reg] * alpha + ps;
            m_old[reg] = mnew;
            #pragma unroll
            for (int db = 0; db < 4; db++) o[db][reg] *= alpha;
        }
        __syncthreads();

        bf16x8 pa0 = *(const bf16x8*)&Ps[w][n16][quad * 8];
        bf16x8 pa1 = *(const bf16x8*)&Ps[w][n16][32 + quad * 8];
        #pragma unroll
        for (int db = 0; db < 4; db++) {
            bf16x8 vb0 = *(const bf16x8*)&Vt[db * 16 + n16][quad * 8];
            bf16x8 vb1 = *(const bf16x8*)&Vt[db * 16 + n16][32 + quad * 8];
            o[db] = __builtin_amdgcn_mfma_f32_16x16x32_bf16(pa0, vb0, o[db], 0, 0, 0);
            o[db] = __builtin_amdgcn_mfma_f32_16x16x32_bf16(pa1, vb1, o[db], 0, 0, 0);
        }
    }

    const int b_ = bh >> 4, h = bh & 15;
    #pragma unroll
    for (int reg = 0; reg < 4; reg++) {
        const float il = 1.0f / l_run[reg];
        const int t_ = q0 + w * 16 + quad * 4 + reg;
        bf16* outr = attn + ((size_t)(b_ * TT + t_)) * DD + h * 64 + n16;
        #pragma unroll
        for (int db = 0; db < 4; db++)
            outr[db * 16] = f2b(o[db][reg] * il);
    }
}

// ---------------------------------------------------------------------------
// Kernel 3: proj MFMA GEMM (global_load_lds staging, unchanged from R4).
// ---------------------------------------------------------------------------
__global__ __launch_bounds__(256) void proj_mfma(
    const ush* __restrict__ a, const ush* __restrict__ wpT,
    const float* __restrict__ bias, float* __restrict__ out)
{
    __shared__ __align__(16) ush As[128 * 32];
    __shared__ __align__(16) ush Bs[128 * 32];

    const int tid  = threadIdx.x;
    const int lane = tid & 63;
    const int w    = tid >> 6;
    const int n16  = lane & 15;
    const int quad = lane >> 4;
    const int row0 = blockIdx.y * 128;
    const int col0 = blockIdx.x * 128;
    const int wrow = (w >> 1) * 64;
    const int wcol = (w & 1) * 64;

    f32x4 acc[4][4];
    #pragma unroll
    for (int mb = 0; mb < 4; mb++)
        #pragma unroll
        for (int nb = 0; nb < 4; nb++) acc[mb][nb] = (f32x4){0.f,0.f,0.f,0.f};

    for (int kk0 = 0; kk0 < DD; kk0 += 32) {
        __syncthreads();
        #pragma unroll
        for (int it = 0; it < 2; it++) {
            int c = it * 256 + tid;
            int r = c >> 2, co = (c & 3) * 8;
            GLOAD_LDS(&a[(size_t)(row0 + r) * DD + kk0 + co], &As[c * 8]);
            GLOAD_LDS(&wpT[(size_t)(col0 + r) * DD + kk0 + co], &Bs[c * 8]);
        }
        __syncthreads();

        bf16x8 af[4];
        #pragma unroll
        for (int mb = 0; mb < 4; mb++)
            af[mb] = *(const bf16x8*)&As[(wrow + mb * 16 + n16) * 32 + quad * 8];
        #pragma unroll
        for (int nb = 0; nb < 4; nb++) {
            bf16x8 bfr = *(const bf16x8*)&Bs[(wcol + nb * 16 + n16) * 32 + quad * 8];
            #pragma unroll
            for (int mb = 0; mb < 4; mb++)
                acc[mb][nb] = __builtin_amdgcn_mfma_f32_16x16x32_bf16(
                    af[mb], bfr, acc[mb][nb], 0, 0, 0);
        }
    }

    #pragma unroll
    for (int nb = 0; nb < 4; nb++) {
        const int gc = col0 + wcol + nb * 16 + n16;
        const float bv = bias[gc];
        #pragma unroll
        for (int mb = 0; mb < 4; mb++) {
            #pragma unroll
            for (int reg = 0; reg < 4; reg++) {
                const int gr = row0 + wrow + mb * 16 + quad * 4 + reg;
                out[(size_t)gr * DD + gc] = acc[mb][nb][reg] + bv;
            }
        }
    }
}

extern "C" void kernel_launch(void* const* d_in, const int* in_sizes, int n_in,
                              void* d_out, int out_size, void* d_ws, size_t ws_size,
                              hipStream_t stream) {
    const float *x = nullptr, *w_attn = nullptr, *b_attn = nullptr,
                *w_proj = nullptr, *b_proj = nullptr;
    for (int i = 0; i < n_in; i++) {
        switch (in_sizes[i]) {
            case 4194304: x      = (const float*)d_in[i]; break;
            case 3145728: w_attn = (const float*)d_in[i]; break;
            case 3072:    b_attn = (const float*)d_in[i]; break;
            case 1048576: w_proj = (const float*)d_in[i]; break;
            case 1024:    b_proj = (const float*)d_in[i]; break;
            default: break;
        }
    }
    if (!x || !w_attn || !b_attn || !w_proj || !b_proj) return;

    float* out_a = (float*)d_out;
    float* out_k = out_a + (size_t)MM * DD;
    float* out_v = out_k + (size_t)BB * HH * TT * DHH;

    const size_t MB = 1024 * 1024;
    char* wsc = (char*)d_ws;
    // ws: [0,6MB) wT (dead after qkv) / [0,8MB) attnws ; [8,16MB) qws (dead
    // after flash) / [8,10MB) wpT ; fast path adds [16,24MB) kbf, [24,32MB)
    // vtb.  xbf (8MB) lives in d_out's out_a region (dead until proj_mfma).
    ush*  wT     = (ush*)(wsc + 0);
    bf16* attnws = (bf16*)(wsc + 0);
    bf16* qws    = (bf16*)(wsc + 8 * MB);
    ush*  wpT    = (ush*)(wsc + 8 * MB);
    ush*  xbf    = (ush*)d_out;

    if (ws_size >= 32 * MB) {
        ush* kbf = (ush*)(wsc + 16 * MB);
        ush* vtb = (ush*)(wsc + 24 * MB);
        cvt_x<<<dim3(MM * DD / (256 * 8)), 256, 0, stream>>>(x, xbf);
        transpose_cvt<<<dim3(N3 / 64, DD / 64), 256, 0, stream>>>(w_attn, wT, DD, N3);
        qkv_mfma<<<dim3(N3 / 128, MM / 128), 256, 0, stream>>>(
            xbf, wT, b_attn, qws, out_k, out_v, kbf, vtb, 1);
        flash_attn_v4<<<dim3(TT / 64, BB * HH), 256, 0, stream>>>(
            (const ush*)qws, kbf, vtb, attnws);
        transpose_cvt<<<dim3(DD / 64, DD / 64), 256, 0, stream>>>(w_proj, wpT, DD, DD);
        proj_mfma<<<dim3(DD / 128, MM / 128), 256, 0, stream>>>(
            (const ush*)attnws, wpT, b_proj, out_a);
    } else if (ws_size >= 16 * MB) {
        cvt_x<<<dim3(MM * DD / (256 * 8)), 256, 0, stream>>>(x, xbf);
        transpose_cvt<<<dim3(N3 / 64, DD / 64), 256, 0, stream>>>(w_attn, wT, DD, N3);
        qkv_mfma<<<dim3(N3 / 128, MM / 128), 256, 0, stream>>>(
            xbf, wT, b_attn, qws, out_k, out_v, nullptr, nullptr, 0);
        flash_attn_mfma<<<dim3(TT / 64, BB * HH), 256, 0, stream>>>(
            qws, out_k, out_v, attnws);
        transpose_cvt<<<dim3(DD / 64, DD / 64), 256, 0, stream>>>(w_proj, wpT, DD, DD);
        proj_mfma<<<dim3(DD / 128, MM / 128), 256, 0, stream>>>(
            (const ush*)attnws, wpT, b_proj, out_a);
    }
}

// Round 6
// 200.520 us; speedup vs baseline: 1.1148x; 1.1148x over previous
//
#include <hip/hip_runtime.h>
#include <hip/hip_bf16.h>

typedef __hip_bfloat16 bf16;
typedef unsigned short ush;
typedef __attribute__((ext_vector_type(8))) short bf16x8;
typedef __attribute__((ext_vector_type(4))) float f32x4;

#define BB 2
#define TT 2048
#define DD 1024
#define HH 16
#define DHH 64
#define MM (BB*TT)      // 4096 rows
#define N3 (3*DD)       // 3072

__device__ __forceinline__ bf16  f2b(float x){ return __float2bfloat16(x); }
__device__ __forceinline__ ush   f2bu(float x){ bf16 h = __float2bfloat16(x); return *(ush*)&h; }

#define GLOAD_LDS(gp, lp) \
    __builtin_amdgcn_global_load_lds( \
        (const __attribute__((address_space(1))) void*)(gp), \
        (__attribute__((address_space(3))) void*)(lp), 16, 0, 0)

// ---------------------------------------------------------------------------
// cvt_x: x f32 [4096][1024] -> bf16 into d_out's out_a region (dead there
// until proj_mfma overwrites it).
// ---------------------------------------------------------------------------
__global__ __launch_bounds__(256) void cvt_x(
    const float* __restrict__ src, ush* __restrict__ dst)
{
    const size_t i = ((size_t)blockIdx.x * 256 + threadIdx.x) * 8;
    float4 a = *(const float4*)&src[i];
    float4 b = *(const float4*)&src[i + 4];
    ushort4 u0; u0.x = f2bu(a.x); u0.y = f2bu(a.y); u0.z = f2bu(a.z); u0.w = f2bu(a.w);
    ushort4 u1; u1.x = f2bu(b.x); u1.y = f2bu(b.y); u1.z = f2bu(b.z); u1.w = f2bu(b.w);
    *(ushort4*)&dst[i] = u0;
    *(ushort4*)&dst[i + 4] = u1;
}

// ---------------------------------------------------------------------------
// Transpose+convert: dst[c][r] = bf16(src[r][c]). src is [R][C] f32.
// ---------------------------------------------------------------------------
__global__ __launch_bounds__(256) void transpose_cvt(
    const float* __restrict__ src, ush* __restrict__ dst, int R, int C)
{
    __shared__ ush T[64][68];
    const int tid = threadIdx.x;
    const int c0 = blockIdx.x * 64;
    const int r0 = blockIdx.y * 64;

    #pragma unroll
    for (int it = 0; it < 4; it++) {
        int idx = it * 256 + tid;
        int i = idx >> 4, jf = idx & 15;
        float4 v = *(const float4*)&src[(size_t)(r0 + i) * C + c0 + jf * 4];
        T[jf * 4 + 0][i] = f2bu(v.x);
        T[jf * 4 + 1][i] = f2bu(v.y);
        T[jf * 4 + 2][i] = f2bu(v.z);
        T[jf * 4 + 3][i] = f2bu(v.w);
    }
    __syncthreads();
    #pragma unroll
    for (int it = 0; it < 4; it++) {
        int idx = it * 256 + tid;
        int j = idx >> 4, i4 = idx & 15;
        *(ushort4*)&dst[(size_t)(c0 + j) * R + r0 + i4 * 4] =
            *(const ushort4*)&T[j][i4 * 4];
    }
}

// ---------------------------------------------------------------------------
// Kernel 1: QKV MFMA GEMM, m97 structure (global_load_lds width=16, linear
// LDS). Fast path (write_bf=1) pre-scales q by 0.25*log2(e) so the flash
// kernel's exp2 needs NO multiply (relative bf16 rounding error is scale-
// invariant). Fallback path (write_bf=0) writes unscaled q.
// ---------------------------------------------------------------------------
__global__ __launch_bounds__(256) void qkv_mfma(
    const ush* __restrict__ xbf, const ush* __restrict__ wT,
    const float* __restrict__ bias,
    bf16* __restrict__ qws, float* __restrict__ kout, float* __restrict__ vout,
    ush* __restrict__ kbf, ush* __restrict__ vtb, int write_bf)
{
    __shared__ __align__(16) ush As[128 * 32];
    __shared__ __align__(16) ush Bs[128 * 32];

    const int tid  = threadIdx.x;
    const int lane = tid & 63;
    const int w    = tid >> 6;
    const int n16  = lane & 15;
    const int quad = lane >> 4;
    const int row0 = blockIdx.y * 128;
    const int col0 = blockIdx.x * 128;
    const int wrow = (w >> 1) * 64;
    const int wcol = (w & 1) * 64;

    f32x4 acc[4][4];
    #pragma unroll
    for (int mb = 0; mb < 4; mb++)
        #pragma unroll
        for (int nb = 0; nb < 4; nb++) acc[mb][nb] = (f32x4){0.f,0.f,0.f,0.f};

    for (int kk0 = 0; kk0 < DD; kk0 += 32) {
        __syncthreads();
        #pragma unroll
        for (int it = 0; it < 2; it++) {
            int c = it * 256 + tid;
            int r = c >> 2, co = (c & 3) * 8;
            GLOAD_LDS(&xbf[(size_t)(row0 + r) * DD + kk0 + co], &As[c * 8]);
            GLOAD_LDS(&wT[(size_t)(col0 + r) * DD + kk0 + co], &Bs[c * 8]);
        }
        __syncthreads();

        bf16x8 af[4];
        #pragma unroll
        for (int mb = 0; mb < 4; mb++)
            af[mb] = *(const bf16x8*)&As[(wrow + mb * 16 + n16) * 32 + quad * 8];
        #pragma unroll
        for (int nb = 0; nb < 4; nb++) {
            bf16x8 bfr = *(const bf16x8*)&Bs[(wcol + nb * 16 + n16) * 32 + quad * 8];
            #pragma unroll
            for (int mb = 0; mb < 4; mb++)
                acc[mb][nb] = __builtin_amdgcn_mfma_f32_16x16x32_bf16(
                    af[mb], bfr, acc[mb][nb], 0, 0, 0);
        }
    }

    const float qsc = write_bf ? 0.36067376022224085f : 1.0f; // 0.25*log2(e)

    #pragma unroll
    for (int nb = 0; nb < 4; nb++) {
        const int gc = col0 + wcol + nb * 16 + n16;
        const float bv = bias[gc];
        const int which = gc >> 10;
        const int h = (gc & 1023) >> 6;
        const int d = gc & 63;
        #pragma unroll
        for (int mb = 0; mb < 4; mb++) {
            float vv[4];
            #pragma unroll
            for (int reg = 0; reg < 4; reg++) vv[reg] = acc[mb][nb][reg] + bv;
            const int gr0 = row0 + wrow + mb * 16 + quad * 4;  // 4 consecutive rows
            const int b_ = gr0 >> 11, t0 = gr0 & 2047;
            const int bh = b_ * HH + h;
            const size_t tbase = ((size_t)bh * TT + t0) * DHH + d;
            if (which == 0) {
                #pragma unroll
                for (int reg = 0; reg < 4; reg++)
                    qws[tbase + (size_t)reg * DHH] = f2b(vv[reg] * qsc);
            } else if (which == 1) {
                #pragma unroll
                for (int reg = 0; reg < 4; reg++) kout[tbase + (size_t)reg * DHH] = vv[reg];
                if (write_bf) {
                    #pragma unroll
                    for (int reg = 0; reg < 4; reg++)
                        kbf[tbase + (size_t)reg * DHH] = f2bu(vv[reg]);
                }
            } else {
                #pragma unroll
                for (int reg = 0; reg < 4; reg++) vout[tbase + (size_t)reg * DHH] = vv[reg];
                if (write_bf) {
                    ushort4 u;
                    u.x = f2bu(vv[0]); u.y = f2bu(vv[1]);
                    u.z = f2bu(vv[2]); u.w = f2bu(vv[3]);
                    *(ushort4*)&vtb[((size_t)bh * DHH + d) * TT + t0] = u;
                }
            }
        }
    }
}

// ---------------------------------------------------------------------------
// Kernel 2 FAST PATH v5 = R4's proven v3 structure (57.4 us: pitch 72,
// single-buffered Ks/Vt, load-early/write-late, 2 barriers/tile) with ONLY
// the LDS-layout-neutral VALU trims from R5:
//  - exp2f(s) with NO multiply (q pre-scaled by 0.25*log2e in qkv).
//  - causal mask computed ONLY on the diagonal tile (kt==qi).
// R5 lesson (measured): pitch 70 = 140B rows breaks ds_read_b128 16B
// alignment -> conflicts DOUBLE; pitch for b128 tiles must be a multiple
// of 8 shorts. Double-buffering grew LDS 27.6->45KB, occupancy 24.5->18.7.
// ---------------------------------------------------------------------------
__global__ __launch_bounds__(256) void flash_attn_v5(
    const ush* __restrict__ qin, const ush* __restrict__ kbf,
    const ush* __restrict__ vtb, bf16* __restrict__ attn)
{
    __shared__ __align__(16) ush Ks[64][72];
    __shared__ __align__(16) ush Vt[64][72];
    __shared__ __align__(16) ush Ps[4][16][72];

    const int tid  = threadIdx.x;
    const int lane = tid & 63;
    const int w    = tid >> 6;
    const int n16  = lane & 15;
    const int quad = lane >> 4;
    const int bh = blockIdx.y;       // 0..31
    const int qi = (bh & 8) ? (31 - (int)blockIdx.x) : (int)blockIdx.x;
    const int q0 = qi * 64;
    const ush* Qb  = qin + (size_t)bh * TT * DHH;
    const ush* Kb  = kbf + (size_t)bh * TT * DHH;
    const ush* Vtb = vtb + (size_t)bh * DHH * TT;
    const int b_ = bh >> 4, h = bh & 15;

    // Q fragments (pre-scaled by 0.25*log2e) straight to registers
    const ush* Qp = Qb + (size_t)(q0 + w * 16 + n16) * DHH + quad * 8;
    const bf16x8 qa0 = *(const bf16x8*)&Qp[0];
    const bf16x8 qa1 = *(const bf16x8*)&Qp[32];

    const int r0c = tid >> 3, c8c = (tid & 7) * 8;
    const int r1c = (256 + tid) >> 3, c8c1 = ((256 + tid) & 7) * 8;

    bf16x8 kst[2], vst[2];
    {   // prologue: load tile 0
        const ush* Kp = Kb;
        const ush* Vp = Vtb;
        kst[0] = *(const bf16x8*)&Kp[(size_t)r0c * DHH + c8c];
        kst[1] = *(const bf16x8*)&Kp[(size_t)r1c * DHH + c8c1];
        vst[0] = *(const bf16x8*)&Vp[(size_t)r0c * TT + c8c];
        vst[1] = *(const bf16x8*)&Vp[(size_t)r1c * TT + c8c1];
    }

    f32x4 o[4];
    #pragma unroll
    for (int db = 0; db < 4; db++) o[db] = (f32x4){0.f, 0.f, 0.f, 0.f};
    float lsum[4] = {0.f, 0.f, 0.f, 0.f};

    const int rloc = w * 16 + quad * 4;      // local row base within the tile

    for (int kt = 0; kt <= qi; kt++) {
        __syncthreads();   // all waves done reading previous tile's LDS
        *(bf16x8*)&Ks[r0c][c8c]  = kst[0];
        *(bf16x8*)&Ks[r1c][c8c1] = kst[1];
        *(bf16x8*)&Vt[r0c][c8c]  = vst[0];
        *(bf16x8*)&Vt[r1c][c8c1] = vst[1];
        __syncthreads();   // staging visible

        // issue NEXT tile's global loads now -> latency hides under compute
        if (kt < qi) {
            const ush* Kp = Kb + (size_t)((kt + 1) * 64) * DHH;
            const ush* Vp = Vtb + (kt + 1) * 64;
            kst[0] = *(const bf16x8*)&Kp[(size_t)r0c * DHH + c8c];
            kst[1] = *(const bf16x8*)&Kp[(size_t)r1c * DHH + c8c1];
            vst[0] = *(const bf16x8*)&Vp[(size_t)r0c * TT + c8c];
            vst[1] = *(const bf16x8*)&Vp[(size_t)r1c * TT + c8c1];
        }

        f32x4 s[4];
        #pragma unroll
        for (int cb = 0; cb < 4; cb++) {
            bf16x8 kb0 = *(const bf16x8*)&Ks[cb * 16 + n16][quad * 8];
            bf16x8 kb1 = *(const bf16x8*)&Ks[cb * 16 + n16][32 + quad * 8];
            f32x4 acc = (f32x4){0.f, 0.f, 0.f, 0.f};
            acc = __builtin_amdgcn_mfma_f32_16x16x32_bf16(qa0, kb0, acc, 0, 0, 0);
            acc = __builtin_amdgcn_mfma_f32_16x16x32_bf16(qa1, kb1, acc, 0, 0, 0);
            s[cb] = acc;
        }

        // exp phase: shift-free exp2 (q pre-scaled); mask only on diagonal tile
        if (kt == qi) {
            #pragma unroll
            for (int reg = 0; reg < 4; reg++) {
                #pragma unroll
                for (int cb = 0; cb < 4; cb++) {
                    float p = exp2f(s[cb][reg]);
                    if (cb * 16 + n16 > rloc + reg) p = 0.f;
                    lsum[reg] += p;
                    Ps[w][quad * 4 + reg][cb * 16 + n16] = f2bu(p);
                }
            }
        } else {
            #pragma unroll
            for (int reg = 0; reg < 4; reg++) {
                #pragma unroll
                for (int cb = 0; cb < 4; cb++) {
                    float p = exp2f(s[cb][reg]);
                    lsum[reg] += p;
                    Ps[w][quad * 4 + reg][cb * 16 + n16] = f2bu(p);
                }
            }
        }
        // NO barrier: Ps[w] is read only by wave w (same-wave lgkmcnt ordering)

        bf16x8 pa0 = *(const bf16x8*)&Ps[w][n16][quad * 8];
        bf16x8 pa1 = *(const bf16x8*)&Ps[w][n16][32 + quad * 8];
        #pragma unroll
        for (int db = 0; db < 4; db++) {
            bf16x8 vb0 = *(const bf16x8*)&Vt[db * 16 + n16][quad * 8];
            bf16x8 vb1 = *(const bf16x8*)&Vt[db * 16 + n16][32 + quad * 8];
            o[db] = __builtin_amdgcn_mfma_f32_16x16x32_bf16(pa0, vb0, o[db], 0, 0, 0);
            o[db] = __builtin_amdgcn_mfma_f32_16x16x32_bf16(pa1, vb1, o[db], 0, 0, 0);
        }
    }

    const int grow_base = q0 + rloc;
    #pragma unroll
    for (int reg = 0; reg < 4; reg++) {
        float ls = lsum[reg];
        #pragma unroll
        for (int off = 1; off < 16; off <<= 1)
            ls += __shfl_xor(ls, off);
        const float il = 1.0f / ls;
        const int t_ = grow_base + reg;
        bf16* outr = attn + ((size_t)(b_ * TT + t_)) * DD + h * 64 + n16;
        #pragma unroll
        for (int db = 0; db < 4; db++)
            outr[db * 16] = f2b(o[db][reg] * il);
    }
}

// ---------------------------------------------------------------------------
// Kernel 2 FALLBACK (exact R7 kernel): f32 K/V from d_out, unscaled q.
// ---------------------------------------------------------------------------
__global__ __launch_bounds__(256) void flash_attn_mfma(
    const bf16* __restrict__ qin, const float* __restrict__ kin,
    const float* __restrict__ vin, bf16* __restrict__ attn)
{
    __shared__ __align__(16) ush Qs[64][72];
    __shared__ __align__(16) ush Ks[64][72];
    __shared__ __align__(16) ush Vt[64][72];
    __shared__ __align__(16) ush Ps[4][16][72];

    const int tid  = threadIdx.x;
    const int lane = tid & 63;
    const int w    = tid >> 6;
    const int n16  = lane & 15;
    const int quad = lane >> 4;
    const int qi = blockIdx.x;
    const int bh = blockIdx.y;
    const int q0 = qi * 64;

    const ush*   Qp = (const ush*)qin + ((size_t)bh * TT + q0) * DHH;
    const float* Kb = kin + (size_t)bh * TT * DHH;
    const float* Vb = vin + (size_t)bh * TT * DHH;

    #pragma unroll
    for (int it = 0; it < 4; it++) {
        int idx = (it * 256 + tid) * 4;
        int r = idx >> 6, d = idx & 63;
        *(ushort4*)&Qs[r][d] = *(const ushort4*)&Qp[idx];
    }

    f32x4 o[4];
    #pragma unroll
    for (int db = 0; db < 4; db++) o[db] = (f32x4){0.f, 0.f, 0.f, 0.f};
    float m_old[4] = {-1e30f, -1e30f, -1e30f, -1e30f};
    float l_run[4] = {0.f, 0.f, 0.f, 0.f};

    for (int kt = 0; kt <= qi; kt++) {
        const float* Kp = Kb + (size_t)(kt * 64) * DHH;
        const float* Vp = Vb + (size_t)(kt * 64) * DHH;
        __syncthreads();
        #pragma unroll
        for (int it = 0; it < 4; it++) {
            int idx = (it * 256 + tid) * 4;
            int c = idx >> 6, d = idx & 63;
            float4 kv = *(const float4*)&Kp[idx];
            ushort4 kb;
            kb.x = f2bu(kv.x); kb.y = f2bu(kv.y); kb.z = f2bu(kv.z); kb.w = f2bu(kv.w);
            *(ushort4*)&Ks[c][d] = kb;
        }
        #pragma unroll
        for (int it = 0; it < 4; it++) {
            int c = tid & 63, d0 = (tid >> 6) * 4 + it * 16;
            float4 vv = *(const float4*)&Vp[c * 64 + d0];
            Vt[d0 + 0][c] = f2bu(vv.x);
            Vt[d0 + 1][c] = f2bu(vv.y);
            Vt[d0 + 2][c] = f2bu(vv.z);
            Vt[d0 + 3][c] = f2bu(vv.w);
        }
        __syncthreads();

        bf16x8 qa0 = *(const bf16x8*)&Qs[w * 16 + n16][quad * 8];
        bf16x8 qa1 = *(const bf16x8*)&Qs[w * 16 + n16][32 + quad * 8];
        f32x4 s[4];
        #pragma unroll
        for (int cb = 0; cb < 4; cb++) {
            bf16x8 kb0 = *(const bf16x8*)&Ks[cb * 16 + n16][quad * 8];
            bf16x8 kb1 = *(const bf16x8*)&Ks[cb * 16 + n16][32 + quad * 8];
            f32x4 acc = (f32x4){0.f, 0.f, 0.f, 0.f};
            acc = __builtin_amdgcn_mfma_f32_16x16x32_bf16(qa0, kb0, acc, 0, 0, 0);
            acc = __builtin_amdgcn_mfma_f32_16x16x32_bf16(qa1, kb1, acc, 0, 0, 0);
            s[cb] = acc;
        }

        const int grow_base = q0 + w * 16 + quad * 4;
        const int gcol_base = kt * 64 + n16;
        #pragma unroll
        for (int reg = 0; reg < 4; reg++) {
            float sv[4];
            float pm = -1e30f;
            #pragma unroll
            for (int cb = 0; cb < 4; cb++) {
                float v = s[cb][reg] * 0.25f;
                if (gcol_base + cb * 16 > grow_base + reg) v = -1e10f;
                sv[cb] = v;
                pm = fmaxf(pm, v);
            }
            #pragma unroll
            for (int off = 1; off < 16; off <<= 1)
                pm = fmaxf(pm, __shfl_xor(pm, off));
            float mnew = fmaxf(m_old[reg], pm);
            float alpha = __expf(m_old[reg] - mnew);
            float ps = 0.f;
            #pragma unroll
            for (int cb = 0; cb < 4; cb++) {
                float p = __expf(sv[cb] - mnew);
                Ps[w][quad * 4 + reg][cb * 16 + n16] = f2bu(p);
                ps += p;
            }
            #pragma unroll
            for (int off = 1; off < 16; off <<= 1)
                ps += __shfl_xor(ps, off);
            l_run[reg] = l_run[reg] * alpha + ps;
            m_old[reg] = mnew;
            #pragma unroll
            for (int db = 0; db < 4; db++) o[db][reg] *= alpha;
        }
        __syncthreads();

        bf16x8 pa0 = *(const bf16x8*)&Ps[w][n16][quad * 8];
        bf16x8 pa1 = *(const bf16x8*)&Ps[w][n16][32 + quad * 8];
        #pragma unroll
        for (int db = 0; db < 4; db++) {
            bf16x8 vb0 = *(const bf16x8*)&Vt[db * 16 + n16][quad * 8];
            bf16x8 vb1 = *(const bf16x8*)&Vt[db * 16 + n16][32 + quad * 8];
            o[db] = __builtin_amdgcn_mfma_f32_16x16x32_bf16(pa0, vb0, o[db], 0, 0, 0);
            o[db] = __builtin_amdgcn_mfma_f32_16x16x32_bf16(pa1, vb1, o[db], 0, 0, 0);
        }
    }

    const int b_ = bh >> 4, h = bh & 15;
    #pragma unroll
    for (int reg = 0; reg < 4; reg++) {
        const float il = 1.0f / l_run[reg];
        const int t_ = q0 + w * 16 + quad * 4 + reg;
        bf16* outr = attn + ((size_t)(b_ * TT + t_)) * DD + h * 64 + n16;
        #pragma unroll
        for (int db = 0; db < 4; db++)
            outr[db * 16] = f2b(o[db][reg] * il);
    }
}

// ---------------------------------------------------------------------------
// Kernel 3: proj MFMA GEMM (global_load_lds staging, unchanged from R4).
// ---------------------------------------------------------------------------
__global__ __launch_bounds__(256) void proj_mfma(
    const ush* __restrict__ a, const ush* __restrict__ wpT,
    const float* __restrict__ bias, float* __restrict__ out)
{
    __shared__ __align__(16) ush As[128 * 32];
    __shared__ __align__(16) ush Bs[128 * 32];

    const int tid  = threadIdx.x;
    const int lane = tid & 63;
    const int w    = tid >> 6;
    const int n16  = lane & 15;
    const int quad = lane >> 4;
    const int row0 = blockIdx.y * 128;
    const int col0 = blockIdx.x * 128;
    const int wrow = (w >> 1) * 64;
    const int wcol = (w & 1) * 64;

    f32x4 acc[4][4];
    #pragma unroll
    for (int mb = 0; mb < 4; mb++)
        #pragma unroll
        for (int nb = 0; nb < 4; nb++) acc[mb][nb] = (f32x4){0.f,0.f,0.f,0.f};

    for (int kk0 = 0; kk0 < DD; kk0 += 32) {
        __syncthreads();
        #pragma unroll
        for (int it = 0; it < 2; it++) {
            int c = it * 256 + tid;
            int r = c >> 2, co = (c & 3) * 8;
            GLOAD_LDS(&a[(size_t)(row0 + r) * DD + kk0 + co], &As[c * 8]);
            GLOAD_LDS(&wpT[(size_t)(col0 + r) * DD + kk0 + co], &Bs[c * 8]);
        }
        __syncthreads();

        bf16x8 af[4];
        #pragma unroll
        for (int mb = 0; mb < 4; mb++)
            af[mb] = *(const bf16x8*)&As[(wrow + mb * 16 + n16) * 32 + quad * 8];
        #pragma unroll
        for (int nb = 0; nb < 4; nb++) {
            bf16x8 bfr = *(const bf16x8*)&Bs[(wcol + nb * 16 + n16) * 32 + quad * 8];
            #pragma unroll
            for (int mb = 0; mb < 4; mb++)
                acc[mb][nb] = __builtin_amdgcn_mfma_f32_16x16x32_bf16(
                    af[mb], bfr, acc[mb][nb], 0, 0, 0);
        }
    }

    #pragma unroll
    for (int nb = 0; nb < 4; nb++) {
        const int gc = col0 + wcol + nb * 16 + n16;
        const float bv = bias[gc];
        #pragma unroll
        for (int mb = 0; mb < 4; mb++) {
            #pragma unroll
            for (int reg = 0; reg < 4; reg++) {
                const int gr = row0 + wrow + mb * 16 + quad * 4 + reg;
                out[(size_t)gr * DD + gc] = acc[mb][nb][reg] + bv;
            }
        }
    }
}

extern "C" void kernel_launch(void* const* d_in, const int* in_sizes, int n_in,
                              void* d_out, int out_size, void* d_ws, size_t ws_size,
                              hipStream_t stream) {
    const float *x = nullptr, *w_attn = nullptr, *b_attn = nullptr,
                *w_proj = nullptr, *b_proj = nullptr;
    for (int i = 0; i < n_in; i++) {
        switch (in_sizes[i]) {
            case 4194304: x      = (const float*)d_in[i]; break;
            case 3145728: w_attn = (const float*)d_in[i]; break;
            case 3072:    b_attn = (const float*)d_in[i]; break;
            case 1048576: w_proj = (const float*)d_in[i]; break;
            case 1024:    b_proj = (const float*)d_in[i]; break;
            default: break;
        }
    }
    if (!x || !w_attn || !b_attn || !w_proj || !b_proj) return;

    float* out_a = (float*)d_out;
    float* out_k = out_a + (size_t)MM * DD;
    float* out_v = out_k + (size_t)BB * HH * TT * DHH;

    const size_t MB = 1024 * 1024;
    char* wsc = (char*)d_ws;
    // ws: [0,6MB) wT (dead after qkv) / [0,8MB) attnws ; [8,16MB) qws (dead
    // after flash) / [8,10MB) wpT ; fast path adds [16,24MB) kbf, [24,32MB)
    // vtb.  xbf (8MB) lives in d_out's out_a region (dead until proj_mfma).
    ush*  wT     = (ush*)(wsc + 0);
    bf16* attnws = (bf16*)(wsc + 0);
    bf16* qws    = (bf16*)(wsc + 8 * MB);
    ush*  wpT    = (ush*)(wsc + 8 * MB);
    ush*  xbf    = (ush*)d_out;

    if (ws_size >= 32 * MB) {
        ush* kbf = (ush*)(wsc + 16 * MB);
        ush* vtb = (ush*)(wsc + 24 * MB);
        cvt_x<<<dim3(MM * DD / (256 * 8)), 256, 0, stream>>>(x, xbf);
        transpose_cvt<<<dim3(N3 / 64, DD / 64), 256, 0, stream>>>(w_attn, wT, DD, N3);
        qkv_mfma<<<dim3(N3 / 128, MM / 128), 256, 0, stream>>>(
            xbf, wT, b_attn, qws, out_k, out_v, kbf, vtb, 1);
        flash_attn_v5<<<dim3(TT / 64, BB * HH), 256, 0, stream>>>(
            (const ush*)qws, kbf, vtb, attnws);
        transpose_cvt<<<dim3(DD / 64, DD / 64), 256, 0, stream>>>(w_proj, wpT, DD, DD);
        proj_mfma<<<dim3(DD / 128, MM / 128), 256, 0, stream>>>(
            (const ush*)attnws, wpT, b_proj, out_a);
    } else if (ws_size >= 16 * MB) {
        cvt_x<<<dim3(MM * DD / (256 * 8)), 256, 0, stream>>>(x, xbf);
        transpose_cvt<<<dim3(N3 / 64, DD / 64), 256, 0, stream>>>(w_attn, wT, DD, N3);
        qkv_mfma<<<dim3(N3 / 128, MM / 128), 256, 0, stream>>>(
            xbf, wT, b_attn, qws, out_k, out_v, nullptr, nullptr, 0);
        flash_attn_mfma<<<dim3(TT / 64, BB * HH), 256, 0, stream>>>(
            qws, out_k, out_v, attnws);
        transpose_cvt<<<dim3(DD / 64, DD / 64), 256, 0, stream>>>(w_proj, wpT, DD, DD);
        proj_mfma<<<dim3(DD / 128, MM / 128), 256, 0, stream>>>(
            (const ush*)attnws, wpT, b_proj, out_a);
    }
}

// Round 7
// 190.900 us; speedup vs baseline: 1.1709x; 1.0504x over previous
//
#include <hip/hip_runtime.h>
#include <hip/hip_bf16.h>

typedef __hip_bfloat16 bf16;
typedef unsigned short ush;
typedef __attribute__((ext_vector_type(8))) short bf16x8;
typedef __attribute__((ext_vector_type(4))) float f32x4;

#define BB 2
#define TT 2048
#define DD 1024
#define HH 16
#define DHH 64
#define MM (BB*TT)      // 4096 rows
#define N3 (3*DD)       // 3072

__device__ __forceinline__ bf16  f2b(float x){ return __float2bfloat16(x); }
__device__ __forceinline__ ush   f2bu(float x){ bf16 h = __float2bfloat16(x); return *(ush*)&h; }

#define GLOAD_LDS(gp, lp) \
    __builtin_amdgcn_global_load_lds( \
        (const __attribute__((address_space(1))) void*)(gp), \
        (__attribute__((address_space(3))) void*)(lp), 16, 0, 0)

// ---------------------------------------------------------------------------
// prep_fused: one dispatch doing (a) cvt_x: x f32 -> xbf bf16 (2048 blocks),
// (b) transpose+cvt w_attn [DD][N3] -> wT [N3][DD] bf16 (768 blocks).
// Outputs disjoint, inputs read-only -> no ordering hazard. Saves a launch.
// ---------------------------------------------------------------------------
__global__ __launch_bounds__(256) void prep_fused(
    const float* __restrict__ x, const float* __restrict__ w_attn,
    ush* __restrict__ xbf, ush* __restrict__ wT)
{
    __shared__ ush T[64][68];
    const int tid = threadIdx.x;
    const int bid = blockIdx.x;

    if (bid < 2048) {       // cvt_x job
        const size_t i = ((size_t)bid * 256 + tid) * 8;
        float4 a = *(const float4*)&x[i];
        float4 b = *(const float4*)&x[i + 4];
        ushort4 u0; u0.x = f2bu(a.x); u0.y = f2bu(a.y); u0.z = f2bu(a.z); u0.w = f2bu(a.w);
        ushort4 u1; u1.x = f2bu(b.x); u1.y = f2bu(b.y); u1.z = f2bu(b.z); u1.w = f2bu(b.w);
        *(ushort4*)&xbf[i] = u0;
        *(ushort4*)&xbf[i + 4] = u1;
        return;
    }
    // transpose job: src=w_attn [R=DD][C=N3], dst=wT [N3][DD]
    const int j  = bid - 2048;
    const int c0 = (j % 48) * 64;
    const int r0 = (j / 48) * 64;
    #pragma unroll
    for (int it = 0; it < 4; it++) {
        int idx = it * 256 + tid;
        int i = idx >> 4, jf = idx & 15;
        float4 v = *(const float4*)&w_attn[(size_t)(r0 + i) * N3 + c0 + jf * 4];
        T[jf * 4 + 0][i] = f2bu(v.x);
        T[jf * 4 + 1][i] = f2bu(v.y);
        T[jf * 4 + 2][i] = f2bu(v.z);
        T[jf * 4 + 3][i] = f2bu(v.w);
    }
    __syncthreads();
    #pragma unroll
    for (int it = 0; it < 4; it++) {
        int idx = it * 256 + tid;
        int jj = idx >> 4, i4 = idx & 15;
        *(ushort4*)&wT[(size_t)(c0 + jj) * DD + r0 + i4 * 4] =
            *(const ushort4*)&T[jj][i4 * 4];
    }
}

// ---------------------------------------------------------------------------
// Transpose+convert: dst[c][r] = bf16(src[r][c]). src is [R][C] f32.
// (still used for w_proj, and by the fallback path)
// ---------------------------------------------------------------------------
__global__ __launch_bounds__(256) void transpose_cvt(
    const float* __restrict__ src, ush* __restrict__ dst, int R, int C)
{
    __shared__ ush T[64][68];
    const int tid = threadIdx.x;
    const int c0 = blockIdx.x * 64;
    const int r0 = blockIdx.y * 64;

    #pragma unroll
    for (int it = 0; it < 4; it++) {
        int idx = it * 256 + tid;
        int i = idx >> 4, jf = idx & 15;
        float4 v = *(const float4*)&src[(size_t)(r0 + i) * C + c0 + jf * 4];
        T[jf * 4 + 0][i] = f2bu(v.x);
        T[jf * 4 + 1][i] = f2bu(v.y);
        T[jf * 4 + 2][i] = f2bu(v.z);
        T[jf * 4 + 3][i] = f2bu(v.w);
    }
    __syncthreads();
    #pragma unroll
    for (int it = 0; it < 4; it++) {
        int idx = it * 256 + tid;
        int j = idx >> 4, i4 = idx & 15;
        *(ushort4*)&dst[(size_t)(c0 + j) * R + r0 + i4 * 4] =
            *(const ushort4*)&T[j][i4 * 4];
    }
}

// ---------------------------------------------------------------------------
// Kernel 1: QKV MFMA GEMM, m97 structure (global_load_lds width=16, linear
// LDS). Fast path (write_bf=1) pre-scales q by 0.25*log2(e) so the flash
// kernel's exp2 needs NO multiply. Unchanged from R6.
// ---------------------------------------------------------------------------
__global__ __launch_bounds__(256) void qkv_mfma(
    const ush* __restrict__ xbf, const ush* __restrict__ wT,
    const float* __restrict__ bias,
    bf16* __restrict__ qws, float* __restrict__ kout, float* __restrict__ vout,
    ush* __restrict__ kbf, ush* __restrict__ vtb, int write_bf)
{
    __shared__ __align__(16) ush As[128 * 32];
    __shared__ __align__(16) ush Bs[128 * 32];

    const int tid  = threadIdx.x;
    const int lane = tid & 63;
    const int w    = tid >> 6;
    const int n16  = lane & 15;
    const int quad = lane >> 4;
    const int row0 = blockIdx.y * 128;
    const int col0 = blockIdx.x * 128;
    const int wrow = (w >> 1) * 64;
    const int wcol = (w & 1) * 64;

    f32x4 acc[4][4];
    #pragma unroll
    for (int mb = 0; mb < 4; mb++)
        #pragma unroll
        for (int nb = 0; nb < 4; nb++) acc[mb][nb] = (f32x4){0.f,0.f,0.f,0.f};

    for (int kk0 = 0; kk0 < DD; kk0 += 32) {
        __syncthreads();
        #pragma unroll
        for (int it = 0; it < 2; it++) {
            int c = it * 256 + tid;
            int r = c >> 2, co = (c & 3) * 8;
            GLOAD_LDS(&xbf[(size_t)(row0 + r) * DD + kk0 + co], &As[c * 8]);
            GLOAD_LDS(&wT[(size_t)(col0 + r) * DD + kk0 + co], &Bs[c * 8]);
        }
        __syncthreads();

        bf16x8 af[4];
        #pragma unroll
        for (int mb = 0; mb < 4; mb++)
            af[mb] = *(const bf16x8*)&As[(wrow + mb * 16 + n16) * 32 + quad * 8];
        #pragma unroll
        for (int nb = 0; nb < 4; nb++) {
            bf16x8 bfr = *(const bf16x8*)&Bs[(wcol + nb * 16 + n16) * 32 + quad * 8];
            #pragma unroll
            for (int mb = 0; mb < 4; mb++)
                acc[mb][nb] = __builtin_amdgcn_mfma_f32_16x16x32_bf16(
                    af[mb], bfr, acc[mb][nb], 0, 0, 0);
        }
    }

    const float qsc = write_bf ? 0.36067376022224085f : 1.0f; // 0.25*log2(e)

    #pragma unroll
    for (int nb = 0; nb < 4; nb++) {
        const int gc = col0 + wcol + nb * 16 + n16;
        const float bv = bias[gc];
        const int which = gc >> 10;
        const int h = (gc & 1023) >> 6;
        const int d = gc & 63;
        #pragma unroll
        for (int mb = 0; mb < 4; mb++) {
            float vv[4];
            #pragma unroll
            for (int reg = 0; reg < 4; reg++) vv[reg] = acc[mb][nb][reg] + bv;
            const int gr0 = row0 + wrow + mb * 16 + quad * 4;  // 4 consecutive rows
            const int b_ = gr0 >> 11, t0 = gr0 & 2047;
            const int bh = b_ * HH + h;
            const size_t tbase = ((size_t)bh * TT + t0) * DHH + d;
            if (which == 0) {
                #pragma unroll
                for (int reg = 0; reg < 4; reg++)
                    qws[tbase + (size_t)reg * DHH] = f2b(vv[reg] * qsc);
            } else if (which == 1) {
                #pragma unroll
                for (int reg = 0; reg < 4; reg++) kout[tbase + (size_t)reg * DHH] = vv[reg];
                if (write_bf) {
                    #pragma unroll
                    for (int reg = 0; reg < 4; reg++)
                        kbf[tbase + (size_t)reg * DHH] = f2bu(vv[reg]);
                }
            } else {
                #pragma unroll
                for (int reg = 0; reg < 4; reg++) vout[tbase + (size_t)reg * DHH] = vv[reg];
                if (write_bf) {
                    ushort4 u;
                    u.x = f2bu(vv[0]); u.y = f2bu(vv[1]);
                    u.z = f2bu(vv[2]); u.w = f2bu(vv[3]);
                    *(ushort4*)&vtb[((size_t)bh * DHH + d) * TT + t0] = u;
                }
            }
        }
    }
}

// ---------------------------------------------------------------------------
// Kernel 2 FAST PATH v6: swapped-operand QK^T kills the Ps LDS bounce.
//  s = mfma(A=K-rows, B=Q) puts scores at [row=k-col][col=q-row=n16]: each
//  lane holds P for ITS OWN q-row. Slot m feeds A with K-rows
//  pi_m(i) = 8*(i>>2) + m + 4*(i&1) + 32*((i>>1)&1), so lane (n16,quad)'s 16
//  values are exactly k in {quad*8..+7} u {32+quad*8..+7} = the pa0/pa1
//  element sets -> pa packed IN-REGISTER, zero cross-lane ops, no Ps array.
//  Supply rows per slot keep the same 8-class LDS bank distribution as the
//  old cb*16+n16 pattern (R5 lesson respected; pitch stays 72).
//  lsum is one scalar/lane (row n16); reduced across quads once at the end,
//  redistributed to output rows (quad*4+reg) with 4 shuffles.
//  Everything else (staging, load-early/write-late, 2 barriers/tile,
//  diagonal-only mask, pre-scaled q -> bare exp2) identical to R6's v5.
// ---------------------------------------------------------------------------
__global__ __launch_bounds__(256) void flash_attn_v6(
    const ush* __restrict__ qin, const ush* __restrict__ kbf,
    const ush* __restrict__ vtb, bf16* __restrict__ attn)
{
    __shared__ __align__(16) ush Ks[64][72];
    __shared__ __align__(16) ush Vt[64][72];

    const int tid  = threadIdx.x;
    const int lane = tid & 63;
    const int w    = tid >> 6;
    const int n16  = lane & 15;
    const int quad = lane >> 4;
    const int bh = blockIdx.y;       // 0..31
    const int qi = (bh & 8) ? (31 - (int)blockIdx.x) : (int)blockIdx.x;
    const int q0 = qi * 64;
    const ush* Qb  = qin + (size_t)bh * TT * DHH;
    const ush* Kb  = kbf + (size_t)bh * TT * DHH;
    const ush* Vtb = vtb + (size_t)bh * DHH * TT;
    const int b_ = bh >> 4, h = bh & 15;

    // Q fragments (pre-scaled by 0.25*log2e). Same load as before; Q is now
    // the B operand (B[col=n16][k=quad*8..+7] = Q[row w*16+n16][d..]).
    const ush* Qp = Qb + (size_t)(q0 + w * 16 + n16) * DHH + quad * 8;
    const bf16x8 qa0 = *(const bf16x8*)&Qp[0];
    const bf16x8 qa1 = *(const bf16x8*)&Qp[32];

    const int r0c = tid >> 3, c8c = (tid & 7) * 8;
    const int r1c = (256 + tid) >> 3, c8c1 = ((256 + tid) & 7) * 8;

    // K supply row base: pi_m(n16) = rsb + m
    const int rsb = ((n16 >> 2) << 3) + ((n16 & 1) << 2) + ((n16 & 2) << 4);
    const int rq  = w * 16 + n16;    // this lane's q-row, local to the 64-tile

    bf16x8 kst[2], vst[2];
    {   // prologue: load tile 0
        const ush* Kp = Kb;
        const ush* Vp = Vtb;
        kst[0] = *(const bf16x8*)&Kp[(size_t)r0c * DHH + c8c];
        kst[1] = *(const bf16x8*)&Kp[(size_t)r1c * DHH + c8c1];
        vst[0] = *(const bf16x8*)&Vp[(size_t)r0c * TT + c8c];
        vst[1] = *(const bf16x8*)&Vp[(size_t)r1c * TT + c8c1];
    }

    f32x4 o[4];
    #pragma unroll
    for (int db = 0; db < 4; db++) o[db] = (f32x4){0.f, 0.f, 0.f, 0.f};
    float lsum = 0.f;

    for (int kt = 0; kt <= qi; kt++) {
        __syncthreads();   // all waves done reading previous tile's LDS
        *(bf16x8*)&Ks[r0c][c8c]  = kst[0];
        *(bf16x8*)&Ks[r1c][c8c1] = kst[1];
        *(bf16x8*)&Vt[r0c][c8c]  = vst[0];
        *(bf16x8*)&Vt[r1c][c8c1] = vst[1];
        __syncthreads();   // staging visible

        // issue NEXT tile's global loads now -> latency hides under compute
        if (kt < qi) {
            const ush* Kp = Kb + (size_t)((kt + 1) * 64) * DHH;
            const ush* Vp = Vtb + (kt + 1) * 64;
            kst[0] = *(const bf16x8*)&Kp[(size_t)r0c * DHH + c8c];
            kst[1] = *(const bf16x8*)&Kp[(size_t)r1c * DHH + c8c1];
            vst[0] = *(const bf16x8*)&Vp[(size_t)r0c * TT + c8c];
            vst[1] = *(const bf16x8*)&Vp[(size_t)r1c * TT + c8c1];
        }

        // swapped QK^T: slot m, A = K rows rsb+m, B = Q
        f32x4 s[4];
        #pragma unroll
        for (int m = 0; m < 4; m++) {
            bf16x8 kb0 = *(const bf16x8*)&Ks[rsb + m][quad * 8];
            bf16x8 kb1 = *(const bf16x8*)&Ks[rsb + m][32 + quad * 8];
            f32x4 a4 = (f32x4){0.f, 0.f, 0.f, 0.f};
            a4 = __builtin_amdgcn_mfma_f32_16x16x32_bf16(kb0, qa0, a4, 0, 0, 0);
            a4 = __builtin_amdgcn_mfma_f32_16x16x32_bf16(kb1, qa1, a4, 0, 0, 0);
            s[m] = a4;
        }

        // exp phase: p[m][reg] = P[q=rq][k = quad*8 + m + 4*(reg&1) + 32*(reg>>1)]
        float p[4][4];
        if (kt == qi) {
            #pragma unroll
            for (int m = 0; m < 4; m++) {
                #pragma unroll
                for (int reg = 0; reg < 4; reg++) {
                    const int kl = quad * 8 + m + ((reg & 1) << 2) + ((reg >> 1) << 5);
                    float pv = exp2f(s[m][reg]);
                    if (kl > rq) pv = 0.f;
                    p[m][reg] = pv;
                    lsum += pv;
                }
            }
        } else {
            #pragma unroll
            for (int m = 0; m < 4; m++) {
                #pragma unroll
                for (int reg = 0; reg < 4; reg++) {
                    float pv = exp2f(s[m][reg]);
                    p[m][reg] = pv;
                    lsum += pv;
                }
            }
        }

        // pack pa in-register: pa0[j] = P[k=quad*8+j], pa1[j] = P[k=32+quad*8+j]
        bf16x8 pa0, pa1;
        #pragma unroll
        for (int m = 0; m < 4; m++) {
            pa0[m]     = (short)f2bu(p[m][0]);
            pa0[m + 4] = (short)f2bu(p[m][1]);
            pa1[m]     = (short)f2bu(p[m][2]);
            pa1[m + 4] = (short)f2bu(p[m][3]);
        }

        #pragma unroll
        for (int db = 0; db < 4; db++) {
            bf16x8 vb0 = *(const bf16x8*)&Vt[db * 16 + n16][quad * 8];
            bf16x8 vb1 = *(const bf16x8*)&Vt[db * 16 + n16][32 + quad * 8];
            o[db] = __builtin_amdgcn_mfma_f32_16x16x32_bf16(pa0, vb0, o[db], 0, 0, 0);
            o[db] = __builtin_amdgcn_mfma_f32_16x16x32_bf16(pa1, vb1, o[db], 0, 0, 0);
        }
    }

    // row-sum: lane (n16, quad) holds partials for q-row n16 -> reduce quads
    float ls = lsum;
    ls += __shfl_xor(ls, 16);
    ls += __shfl_xor(ls, 32);
    // redistribute: output row quad*4+reg's sum lives at lane id (quad*4+reg)
    #pragma unroll
    for (int reg = 0; reg < 4; reg++) {
        const float il = 1.0f / __shfl(ls, quad * 4 + reg);
        const int t_ = q0 + w * 16 + quad * 4 + reg;
        bf16* outr = attn + ((size_t)(b_ * TT + t_)) * DD + h * 64 + n16;
        #pragma unroll
        for (int db = 0; db < 4; db++)
            outr[db * 16] = f2b(o[db][reg] * il);
    }
}

// ---------------------------------------------------------------------------
// Kernel 2 FALLBACK (exact R7 kernel): f32 K/V from d_out, unscaled q.
// ---------------------------------------------------------------------------
__global__ __launch_bounds__(256) void flash_attn_mfma(
    const bf16* __restrict__ qin, const float* __restrict__ kin,
    const float* __restrict__ vin, bf16* __restrict__ attn)
{
    __shared__ __align__(16) ush Qs[64][72];
    __shared__ __align__(16) ush Ks[64][72];
    __shared__ __align__(16) ush Vt[64][72];
    __shared__ __align__(16) ush Ps[4][16][72];

    const int tid  = threadIdx.x;
    const int lane = tid & 63;
    const int w    = tid >> 6;
    const int n16  = lane & 15;
    const int quad = lane >> 4;
    const int qi = blockIdx.x;
    const int bh = blockIdx.y;
    const int q0 = qi * 64;

    const ush*   Qp = (const ush*)qin + ((size_t)bh * TT + q0) * DHH;
    const float* Kb = kin + (size_t)bh * TT * DHH;
    const float* Vb = vin + (size_t)bh * TT * DHH;

    #pragma unroll
    for (int it = 0; it < 4; it++) {
        int idx = (it * 256 + tid) * 4;
        int r = idx >> 6, d = idx & 63;
        *(ushort4*)&Qs[r][d] = *(const ushort4*)&Qp[idx];
    }

    f32x4 o[4];
    #pragma unroll
    for (int db = 0; db < 4; db++) o[db] = (f32x4){0.f, 0.f, 0.f, 0.f};
    float m_old[4] = {-1e30f, -1e30f, -1e30f, -1e30f};
    float l_run[4] = {0.f, 0.f, 0.f, 0.f};

    for (int kt = 0; kt <= qi; kt++) {
        const float* Kp = Kb + (size_t)(kt * 64) * DHH;
        const float* Vp = Vb + (size_t)(kt * 64) * DHH;
        __syncthreads();
        #pragma unroll
        for (int it = 0; it < 4; it++) {
            int idx = (it * 256 + tid) * 4;
            int c = idx >> 6, d = idx & 63;
            float4 kv = *(const float4*)&Kp[idx];
            ushort4 kb;
            kb.x = f2bu(kv.x); kb.y = f2bu(kv.y); kb.z = f2bu(kv.z); kb.w = f2bu(kv.w);
            *(ushort4*)&Ks[c][d] = kb;
        }
        #pragma unroll
        for (int it = 0; it < 4; it++) {
            int c = tid & 63, d0 = (tid >> 6) * 4 + it * 16;
            float4 vv = *(const float4*)&Vp[c * 64 + d0];
            Vt[d0 + 0][c] = f2bu(vv.x);
            Vt[d0 + 1][c] = f2bu(vv.y);
            Vt[d0 + 2][c] = f2bu(vv.z);
            Vt[d0 + 3][c] = f2bu(vv.w);
        }
        __syncthreads();

        bf16x8 qa0 = *(const bf16x8*)&Qs[w * 16 + n16][quad * 8];
        bf16x8 qa1 = *(const bf16x8*)&Qs[w * 16 + n16][32 + quad * 8];
        f32x4 s[4];
        #pragma unroll
        for (int cb = 0; cb < 4; cb++) {
            bf16x8 kb0 = *(const bf16x8*)&Ks[cb * 16 + n16][quad * 8];
            bf16x8 kb1 = *(const bf16x8*)&Ks[cb * 16 + n16][32 + quad * 8];
            f32x4 acc = (f32x4){0.f, 0.f, 0.f, 0.f};
            acc = __builtin_amdgcn_mfma_f32_16x16x32_bf16(qa0, kb0, acc, 0, 0, 0);
            acc = __builtin_amdgcn_mfma_f32_16x16x32_bf16(qa1, kb1, acc, 0, 0, 0);
            s[cb] = acc;
        }

        const int grow_base = q0 + w * 16 + quad * 4;
        const int gcol_base = kt * 64 + n16;
        #pragma unroll
        for (int reg = 0; reg < 4; reg++) {
            float sv[4];
            float pm = -1e30f;
            #pragma unroll
            for (int cb = 0; cb < 4; cb++) {
                float v = s[cb][reg] * 0.25f;
                if (gcol_base + cb * 16 > grow_base + reg) v = -1e10f;
                sv[cb] = v;
                pm = fmaxf(pm, v);
            }
            #pragma unroll
            for (int off = 1; off < 16; off <<= 1)
                pm = fmaxf(pm, __shfl_xor(pm, off));
            float mnew = fmaxf(m_old[reg], pm);
            float alpha = __expf(m_old[reg] - mnew);
            float ps = 0.f;
            #pragma unroll
            for (int cb = 0; cb < 4; cb++) {
                float p = __expf(sv[cb] - mnew);
                Ps[w][quad * 4 + reg][cb * 16 + n16] = f2bu(p);
                ps += p;
            }
            #pragma unroll
            for (int off = 1; off < 16; off <<= 1)
                ps += __shfl_xor(ps, off);
            l_run[reg] = l_run[reg] * alpha + ps;
            m_old[reg] = mnew;
            #pragma unroll
            for (int db = 0; db < 4; db++) o[db][reg] *= alpha;
        }
        __syncthreads();

        bf16x8 pa0 = *(const bf16x8*)&Ps[w][n16][quad * 8];
        bf16x8 pa1 = *(const bf16x8*)&Ps[w][n16][32 + quad * 8];
        #pragma unroll
        for (int db = 0; db < 4; db++) {
            bf16x8 vb0 = *(const bf16x8*)&Vt[db * 16 + n16][quad * 8];
            bf16x8 vb1 = *(const bf16x8*)&Vt[db * 16 + n16][32 + quad * 8];
            o[db] = __builtin_amdgcn_mfma_f32_16x16x32_bf16(pa0, vb0, o[db], 0, 0, 0);
            o[db] = __builtin_amdgcn_mfma_f32_16x16x32_bf16(pa1, vb1, o[db], 0, 0, 0);
        }
    }

    const int b_ = bh >> 4, h = bh & 15;
    #pragma unroll
    for (int reg = 0; reg < 4; reg++) {
        const float il = 1.0f / l_run[reg];
        const int t_ = q0 + w * 16 + quad * 4 + reg;
        bf16* outr = attn + ((size_t)(b_ * TT + t_)) * DD + h * 64 + n16;
        #pragma unroll
        for (int db = 0; db < 4; db++)
            outr[db * 16] = f2b(o[db][reg] * il);
    }
}

// ---------------------------------------------------------------------------
// Kernel 3: proj MFMA GEMM (global_load_lds staging, unchanged).
// ---------------------------------------------------------------------------
__global__ __launch_bounds__(256) void proj_mfma(
    const ush* __restrict__ a, const ush* __restrict__ wpT,
    const float* __restrict__ bias, float* __restrict__ out)
{
    __shared__ __align__(16) ush As[128 * 32];
    __shared__ __align__(16) ush Bs[128 * 32];

    const int tid  = threadIdx.x;
    const int lane = tid & 63;
    const int w    = tid >> 6;
    const int n16  = lane & 15;
    const int quad = lane >> 4;
    const int row0 = blockIdx.y * 128;
    const int col0 = blockIdx.x * 128;
    const int wrow = (w >> 1) * 64;
    const int wcol = (w & 1) * 64;

    f32x4 acc[4][4];
    #pragma unroll
    for (int mb = 0; mb < 4; mb++)
        #pragma unroll
        for (int nb = 0; nb < 4; nb++) acc[mb][nb] = (f32x4){0.f,0.f,0.f,0.f};

    for (int kk0 = 0; kk0 < DD; kk0 += 32) {
        __syncthreads();
        #pragma unroll
        for (int it = 0; it < 2; it++) {
            int c = it * 256 + tid;
            int r = c >> 2, co = (c & 3) * 8;
            GLOAD_LDS(&a[(size_t)(row0 + r) * DD + kk0 + co], &As[c * 8]);
            GLOAD_LDS(&wpT[(size_t)(col0 + r) * DD + kk0 + co], &Bs[c * 8]);
        }
        __syncthreads();

        bf16x8 af[4];
        #pragma unroll
        for (int mb = 0; mb < 4; mb++)
            af[mb] = *(const bf16x8*)&As[(wrow + mb * 16 + n16) * 32 + quad * 8];
        #pragma unroll
        for (int nb = 0; nb < 4; nb++) {
            bf16x8 bfr = *(const bf16x8*)&Bs[(wcol + nb * 16 + n16) * 32 + quad * 8];
            #pragma unroll
            for (int mb = 0; mb < 4; mb++)
                acc[mb][nb] = __builtin_amdgcn_mfma_f32_16x16x32_bf16(
                    af[mb], bfr, acc[mb][nb], 0, 0, 0);
        }
    }

    #pragma unroll
    for (int nb = 0; nb < 4; nb++) {
        const int gc = col0 + wcol + nb * 16 + n16;
        const float bv = bias[gc];
        #pragma unroll
        for (int mb = 0; mb < 4; mb++) {
            #pragma unroll
            for (int reg = 0; reg < 4; reg++) {
                const int gr = row0 + wrow + mb * 16 + quad * 4 + reg;
                out[(size_t)gr * DD + gc] = acc[mb][nb][reg] + bv;
            }
        }
    }
}

extern "C" void kernel_launch(void* const* d_in, const int* in_sizes, int n_in,
                              void* d_out, int out_size, void* d_ws, size_t ws_size,
                              hipStream_t stream) {
    const float *x = nullptr, *w_attn = nullptr, *b_attn = nullptr,
                *w_proj = nullptr, *b_proj = nullptr;
    for (int i = 0; i < n_in; i++) {
        switch (in_sizes[i]) {
            case 4194304: x      = (const float*)d_in[i]; break;
            case 3145728: w_attn = (const float*)d_in[i]; break;
            case 3072:    b_attn = (const float*)d_in[i]; break;
            case 1048576: w_proj = (const float*)d_in[i]; break;
            case 1024:    b_proj = (const float*)d_in[i]; break;
            default: break;
        }
    }
    if (!x || !w_attn || !b_attn || !w_proj || !b_proj) return;

    float* out_a = (float*)d_out;
    float* out_k = out_a + (size_t)MM * DD;
    float* out_v = out_k + (size_t)BB * HH * TT * DHH;

    const size_t MB = 1024 * 1024;
    char* wsc = (char*)d_ws;
    // ws: [0,6MB) wT (dead after qkv) / [0,8MB) attnws ; [8,16MB) qws (dead
    // after flash) / [8,10MB) wpT ; fast path adds [16,24MB) kbf, [24,32MB)
    // vtb.  xbf (8MB) lives in d_out's out_a region (dead until proj_mfma).
    ush*  wT     = (ush*)(wsc + 0);
    bf16* attnws = (bf16*)(wsc + 0);
    bf16* qws    = (bf16*)(wsc + 8 * MB);
    ush*  wpT    = (ush*)(wsc + 8 * MB);
    ush*  xbf    = (ush*)d_out;

    if (ws_size >= 32 * MB) {
        ush* kbf = (ush*)(wsc + 16 * MB);
        ush* vtb = (ush*)(wsc + 24 * MB);
        prep_fused<<<dim3(2048 + 768), 256, 0, stream>>>(x, w_attn, xbf, wT);
        qkv_mfma<<<dim3(N3 / 128, MM / 128), 256, 0, stream>>>(
            xbf, wT, b_attn, qws, out_k, out_v, kbf, vtb, 1);
        flash_attn_v6<<<dim3(TT / 64, BB * HH), 256, 0, stream>>>(
            (const ush*)qws, kbf, vtb, attnws);
        transpose_cvt<<<dim3(DD / 64, DD / 64), 256, 0, stream>>>(w_proj, wpT, DD, DD);
        proj_mfma<<<dim3(DD / 128, MM / 128), 256, 0, stream>>>(
            (const ush*)attnws, wpT, b_proj, out_a);
    } else if (ws_size >= 16 * MB) {
        prep_fused<<<dim3(2048 + 768), 256, 0, stream>>>(x, w_attn, xbf, wT);
        qkv_mfma<<<dim3(N3 / 128, MM / 128), 256, 0, stream>>>(
            xbf, wT, b_attn, qws, out_k, out_v, nullptr, nullptr, 0);
        flash_attn_mfma<<<dim3(TT / 64, BB * HH), 256, 0, stream>>>(
            qws, out_k, out_v, attnws);
        transpose_cvt<<<dim3(DD / 64, DD / 64), 256, 0, stream>>>(w_proj, wpT, DD, DD);
        proj_mfma<<<dim3(DD / 128, MM / 128), 256, 0, stream>>>(
            (const ush*)attnws, wpT, b_proj, out_a);
    }
}